// Round 5
// baseline (5529.161 us; speedup 1.0000x reference)
//
#include <hip/hip_runtime.h>

// SuperpointNeuralOperator on MI355X. Round 5: OUTPUT DTYPE FIX.
// d_out is FLOAT32 (reference outputs are f32/int32 -> "else float*" per the
// harness contract). Rounds 3/4 wrote bf16 u16s; the harness's f32 view put
// outTop bit-pairs (~65500) into Output-1's region -> the bit-identical 65433
// failures. Pipeline numerics were already correct.
// f32 math; bf16 v intermediates in ws (17,180,672 B, byte-identical to the
// round-3-proven-safe footprint). One wave per point, lane = channel (H=64).

#define N_PTS 65536
#define KNN   16
#define HDIM  64
#define KASEL 8
#define NSP   512
#define GSTRIDE 128   // N_PTS / NSP

typedef unsigned short u16;

__device__ __forceinline__ float bf2f(u16 h) {
    return __uint_as_float(((unsigned int)h) << 16);
}
__device__ __forceinline__ u16 f2bfu(float f) {  // round-to-nearest-even
    unsigned int u = __float_as_uint(f);
    unsigned int r = ((u >> 16) & 1u) + 0x7fffu;
    return (u16)((u + r) >> 16);
}
__device__ __forceinline__ float wsum(float v) {
    #pragma unroll
    for (int o = 32; o > 0; o >>= 1) v += __shfl_xor(v, o, 64);
    return v;
}
__device__ __forceinline__ float gelu_exact(float x) {
    return 0.5f * x * (1.0f + erff(x * 0.70710678118654752440f));
}

// ---------------------------------------------------------------- lift ------
__global__ __launch_bounds__(256) void k_lift(
    const float* __restrict__ coords, const float* __restrict__ feat,
    const float* __restrict__ lw, const float* __restrict__ lb,
    u16* __restrict__ vA)
{
    int lane = threadIdx.x & 63, wid = threadIdx.x >> 6;
    float w[9];
    #pragma unroll
    for (int k = 0; k < 9; k++) w[k] = lw[k * 64 + lane];
    float b = lb[lane];
    int i = blockIdx.x * 4 + wid;
    if (i >= N_PTS) return;
    float in[9];
    #pragma unroll
    for (int k = 0; k < 3; k++) in[k] = coords[i * 3 + k];
    #pragma unroll
    for (int k = 0; k < 6; k++) in[3 + k] = feat[i * 6 + k];
    float acc = b;
    #pragma unroll
    for (int k = 0; k < 9; k++) acc = fmaf(in[k], w[k], acc);
    vA[(size_t)i * 64 + lane] = f2bfu(acc);
}

// --------------------------------------------- gnn step (vjf fused) ---------
__global__ __launch_bounds__(256) void k_step(
    const u16* __restrict__ vin, u16* __restrict__ voutB, float* __restrict__ voutF,
    const float* __restrict__ coords, const int* __restrict__ idxp,
    const float* __restrict__ gvi_w, const float* __restrict__ gvi_b,
    const float* __restrict__ gp_w,  const float* __restrict__ gp_b,
    const float* __restrict__ gvj_w,
    const float* __restrict__ gm1_w, const float* __restrict__ gm1_b,
    const float* __restrict__ gm2_w, const float* __restrict__ gm2_b,
    const float* __restrict__ W_w,
    const float* __restrict__ ln_gp, const float* __restrict__ ln_bp,
    float* __restrict__ scores, int lastStep)
{
    // transposed f32 weight tiles in LDS; stride 68 floats keeps float4 reads
    // 16B-aligned and spreads banks.
    __shared__ __align__(16) float sVi[64][68];
    __shared__ __align__(16) float sWw[64][68];
    __shared__ __align__(16) float sGj[64][68];
    __shared__ __align__(16) float rows[4][2][64];
    int lane = threadIdx.x & 63, wid = threadIdx.x >> 6, tid = threadIdx.x;
    for (int e = tid; e < 4096; e += 256) {
        int k = e >> 6, l = e & 63;
        sVi[l][k] = gvi_w[e];
        sWw[l][k] = W_w[e];
        sGj[l][k] = gvj_w[e];
    }
    float gc[64];                               // gm1 column in registers
    #pragma unroll
    for (int k = 0; k < 64; k++) gc[k] = gm1_w[k * 64 + lane];
    float gp0 = gp_w[lane], gp1 = gp_w[64 + lane], gp2 = gp_w[128 + lane];
    float gpb = gp_b[lane], gvib = gvi_b[lane], gm1b = gm1_b[lane];
    float gm2c = gm2_w[lane];
    float gm2b = gm2_b[0];
    float lng = ln_gp[lane], lnb = ln_bp[lane];
    __syncthreads();

    int i = blockIdx.x * 4 + wid;
    if (i >= N_PTS) return;

    float vl = bf2f(vin[(size_t)i * 64 + lane]);
    rows[wid][0][lane] = vl;
    float vi, wv;
    {
        float a0 = 0.f, a1 = 0.f;
        const float* w0 = &sVi[lane][0];
        const float* w1 = &sWw[lane][0];
        #pragma unroll
        for (int kk = 0; kk < 16; kk++) {
            float4 r = *(const float4*)&rows[wid][0][kk * 4];
            float4 x = *(const float4*)(w0 + kk * 4);
            float4 y = *(const float4*)(w1 + kk * 4);
            a0 = fmaf(r.x, x.x, fmaf(r.y, x.y, fmaf(r.z, x.z, fmaf(r.w, x.w, a0))));
            a1 = fmaf(r.x, y.x, fmaf(r.y, y.y, fmaf(r.z, y.z, fmaf(r.w, y.w, a1))));
        }
        vi = a0 + gvib;
        wv = a1;
    }
    float cix = coords[i * 3], ciy = coords[i * 3 + 1], ciz = coords[i * 3 + 2];

    float integral = 0.f;
    for (int k = 0; k < KNN; k++) {
        int j = idxp[i * KNN + k] & (N_PTS - 1);   // mask = cheap OOB insurance
        float rx = coords[j * 3]     - cix;
        float ry = coords[j * 3 + 1] - ciy;
        float rz = coords[j * 3 + 2] - ciz;
        float vjraw = bf2f(vin[(size_t)j * 64 + lane]);
        rows[wid][1][lane] = vjraw;               // stage v_j row (wave-sync)
        float vjf = 0.f;
        {
            const float* wg = &sGj[lane][0];
            #pragma unroll
            for (int kk = 0; kk < 16; kk++) {
                float4 r = *(const float4*)&rows[wid][1][kk * 4];
                float4 gw = *(const float4*)(wg + kk * 4);
                vjf = fmaf(r.x, gw.x, fmaf(r.y, gw.y,
                      fmaf(r.z, gw.z, fmaf(r.w, gw.w, vjf))));
            }
        }
        float g = fmaf(rx, gp0, fmaf(ry, gp1, fmaf(rz, gp2, gpb))) + vi + vjf;
        float h = gelu_exact(g);
        rows[wid][1][lane] = h;                   // overwrite after consume
        float acc = 0.f;
        #pragma unroll
        for (int kk = 0; kk < 16; kk++) {
            float4 h4 = *(const float4*)&rows[wid][1][kk * 4];
            acc = fmaf(h4.x, gc[4*kk+0], fmaf(h4.y, gc[4*kk+1],
                  fmaf(h4.z, gc[4*kk+2], fmaf(h4.w, gc[4*kk+3], acc))));
        }
        float h2 = gelu_exact(acc + gm1b);
        float s  = wsum(h2 * gm2c);
        float G  = 1.f / (1.f + expf(-(s + gm2b)));
        integral = fmaf(G, vjraw, integral);
    }
    integral *= (1.f / 16.f);

    float x = integral + wv;
    x = x > 0.f ? x : 0.f;
    float m   = wsum(x) * (1.f / 64.f);
    float xm  = x - m;
    float var = wsum(xm * xm) * (1.f / 64.f);
    float vn  = xm * (1.f / sqrtf(var + 1e-5f)) * lng + lnb;

    if (lastStep) {
        voutF[(size_t)i * 64 + lane] = vn;        // final v -> d_out (f32)
        float s2 = wsum(vn * vn);
        if (lane == 0) scores[i] = sqrtf(s2);
    } else {
        voutB[(size_t)i * 64 + lane] = f2bfu(vn); // intermediate -> ws (bf16)
    }
}

// ------------------------------------------------ strided argmax anchors ----
__global__ __launch_bounds__(256) void k_anchor(
    const float* __restrict__ scores, const float* __restrict__ coords,
    int* __restrict__ wstop, float* __restrict__ axyz, float* __restrict__ outTop)
{
    int lane = threadIdx.x & 63, wid = threadIdx.x >> 6;
    int g = blockIdx.x * 4 + wid;
    if (g >= NSP) return;
    float s1 = scores[g * GSTRIDE + lane];
    float s2 = scores[g * GSTRIDE + 64 + lane];
    float bv; int bi;
    if (s1 >= s2) { bv = s1; bi = lane; } else { bv = s2; bi = 64 + lane; }
    #pragma unroll
    for (int o = 32; o > 0; o >>= 1) {
        float ov = __shfl_xor(bv, o, 64);
        int   oi = __shfl_xor(bi, o, 64);
        if (ov > bv || (ov == bv && oi < bi)) { bv = ov; bi = oi; }
    }
    int top = g * GSTRIDE + bi;               // <= 65535 -> clip is a no-op
    if (lane == 0) {
        wstop[g] = top;
        outTop[g] = (float)top;               // f32 output
        float ax = coords[top * 3], ay = coords[top * 3 + 1], az = coords[top * 3 + 2];
        axyz[g * 4 + 0] = ax;
        axyz[g * 4 + 1] = ay;
        axyz[g * 4 + 2] = az;
        axyz[g * 4 + 3] = fmaf(ax, ax, fmaf(ay, ay, az * az));
    }
}

// ----------------------------------------- queries = v[top] @ aq + b, /s ----
__global__ __launch_bounds__(256) void k_queries(
    const float* __restrict__ vfin, const int* __restrict__ wstop,
    const float* __restrict__ aq_w, const float* __restrict__ aq_b,
    float* __restrict__ q_s)
{
    __shared__ __align__(16) float rows[4][64];
    int lane = threadIdx.x & 63, wid = threadIdx.x >> 6;
    float w[64];
    #pragma unroll
    for (int k = 0; k < 64; k++) w[k] = aq_w[k * 64 + lane];
    float b = aq_b[lane];
    int g = blockIdx.x * 4 + wid;
    if (g >= NSP) return;
    int tv = wstop[g] & (N_PTS - 1);
    rows[wid][lane] = vfin[(size_t)tv * 64 + lane];
    float acc = b;
    #pragma unroll
    for (int kk = 0; kk < 16; kk++) {
        float4 r = *(const float4*)&rows[wid][kk * 4];
        acc = fmaf(r.x, w[4*kk+0], fmaf(r.y, w[4*kk+1],
              fmaf(r.z, w[4*kk+2], fmaf(r.w, w[4*kk+3], acc))));
    }
    q_s[(size_t)g * 64 + lane] = acc / 2.82842712474619f;   // 64^0.25
}

// ---------------------------- kNN-to-anchors + attention softmax ------------
__global__ __launch_bounds__(256) void k_final(
    const float* __restrict__ vfin, const float* __restrict__ coords,
    const float* __restrict__ ak_w, const float* __restrict__ ak_b,
    const float* __restrict__ axyz, const float* __restrict__ q_s,
    float* __restrict__ outA, float* __restrict__ outNN)
{
    __shared__ __align__(16) float rows[4][64];
    int lane = threadIdx.x & 63, wid = threadIdx.x >> 6;
    float w[64];
    #pragma unroll
    for (int k = 0; k < 64; k++) w[k] = ak_w[k * 64 + lane];
    float kb = ak_b[lane];
    int i = blockIdx.x * 4 + wid;
    if (i >= N_PTS) return;

    float vl = vfin[(size_t)i * 64 + lane];
    rows[wid][lane] = vl;
    float acc = kb;
    #pragma unroll
    for (int kk = 0; kk < 16; kk++) {
        float4 r = *(const float4*)&rows[wid][kk * 4];
        acc = fmaf(r.x, w[4*kk+0], fmaf(r.y, w[4*kk+1],
              fmaf(r.z, w[4*kk+2], fmaf(r.w, w[4*kk+3], acc))));
    }
    float ks = acc / 2.82842712474619f;

    float cx = coords[i * 3], cy = coords[i * 3 + 1], cz = coords[i * 3 + 2];
    float cn2 = fmaf(cx, cx, fmaf(cy, cy, cz * cz));
    float d2v[8];
    #pragma unroll
    for (int m = 0; m < 8; m++) {
        int a = lane + 64 * m;
        float4 av = *(const float4*)&axyz[a * 4];
        float dot = fmaf(cx, av.x, fmaf(cy, av.y, cz * av.z));
        d2v[m] = cn2 + av.w - 2.f * dot;
    }
    // 8x extract-min over 512 candidates; ties -> lower anchor index
    // (matches lax.top_k stability), output order ascending d2.
    unsigned taken = 0;
    int sel[8];
    #pragma unroll
    for (int r = 0; r < KASEL; r++) {
        float bv = 3.4e38f; int bi = 0x7fffffff;
        #pragma unroll
        for (int m = 0; m < 8; m++) {
            if (!((taken >> m) & 1u)) {
                int ai = lane + 64 * m;
                float dv = d2v[m];
                if (dv < bv || (dv == bv && ai < bi)) { bv = dv; bi = ai; }
            }
        }
        #pragma unroll
        for (int o = 32; o > 0; o >>= 1) {
            float ov = __shfl_xor(bv, o, 64);
            int   oi = __shfl_xor(bi, o, 64);
            if (ov < bv || (ov == bv && oi < bi)) { bv = ov; bi = oi; }
        }
        sel[r] = bi & (NSP - 1);              // insurance mask (no-op when correct)
        if ((bi & 63) == lane) taken |= 1u << (bi >> 6);
    }
    float lg[8];
    #pragma unroll
    for (int r = 0; r < KASEL; r++) {
        float q = q_s[(size_t)sel[r] * 64 + lane];
        lg[r] = wsum(ks * q);
    }
    float mx = lg[0];
    #pragma unroll
    for (int r = 1; r < KASEL; r++) mx = fmaxf(mx, lg[r]);
    float e[8], ssum = 0.f;
    #pragma unroll
    for (int r = 0; r < KASEL; r++) { e[r] = expf(lg[r] - mx); ssum += e[r]; }
    if (lane == 0) {
        float inv = 1.f / ssum;
        float4 a0 = make_float4(e[0]*inv, e[1]*inv, e[2]*inv, e[3]*inv);
        float4 a1 = make_float4(e[4]*inv, e[5]*inv, e[6]*inv, e[7]*inv);
        float4 n0 = make_float4((float)sel[0], (float)sel[1], (float)sel[2], (float)sel[3]);
        float4 n1 = make_float4((float)sel[4], (float)sel[5], (float)sel[6], (float)sel[7]);
        *(float4*)&outA [(size_t)i * 8]     = a0;
        *(float4*)&outA [(size_t)i * 8 + 4] = a1;
        *(float4*)&outNN[(size_t)i * 8]     = n0;
        *(float4*)&outNN[(size_t)i * 8 + 4] = n1;
    }
}

// ------------------------------------------------------- beacon kernel -----
__global__ void k_beacon(float* dst, float code) {
    if (threadIdx.x == 0 && blockIdx.x == 0) dst[0] = code;
}

// ---------------------------------------------------------------- launch ----
extern "C" void kernel_launch(void* const* d_in, const int* in_sizes, int n_in,
                              void* d_out, int out_size, void* d_ws, size_t ws_size,
                              hipStream_t stream) {
    (void)n_in;
    const float* coords = (const float*)d_in[0];
    const float* feat   = (const float*)d_in[1];
    const float* lift_w = (const float*)d_in[2];
    const float* lift_b = (const float*)d_in[3];
    const float* gp_w   = (const float*)d_in[4];
    const float* gp_b   = (const float*)d_in[5];
    const float* gvi_w  = (const float*)d_in[6];
    const float* gvi_b  = (const float*)d_in[7];
    const float* gvj_w  = (const float*)d_in[8];
    const float* gm1_w  = (const float*)d_in[9];
    const float* gm1_b  = (const float*)d_in[10];
    const float* gm2_w  = (const float*)d_in[11];
    const float* gm2_b  = (const float*)d_in[12];
    const float* W_w    = (const float*)d_in[13];
    const float* ln_g   = (const float*)d_in[14];
    const float* ln_b   = (const float*)d_in[15];
    const float* ak_w   = (const float*)d_in[16];
    const float* ak_b   = (const float*)d_in[17];
    const float* aq_w   = (const float*)d_in[18];
    const float* aq_b   = (const float*)d_in[19];
    const int* idx      = (const int*)d_in[20];
    // d_in[21] = n_sp scalar (unused; NSP hard-coded)

    // workspace layout: 17,180,672 B, byte-identical to the round-3-proven size
    char* ws = (char*)d_ws;
    size_t o = 0;
    u16*   vbufA  = (u16*)  (ws + o); o += (size_t)N_PTS * 64 * 2;  // 8,388,608
    u16*   vbufB  = (u16*)  (ws + o); o += (size_t)N_PTS * 64 * 2;  // 8,388,608
    float* scores = (float*)(ws + o); o += (size_t)N_PTS * 4;       //   262,144
    int*   wstop  = (int*)  (ws + o); o += (size_t)NSP * 4;         //     2,048
    float* axyz   = (float*)(ws + o); o += (size_t)NSP * 4 * 4;     //     8,192
    float* q_s    = (float*)(ws + o); o += (size_t)NSP * 64 * 4;    //   131,072
    const size_t WS_NEED = o;  // 17,180,672

    // d_out layout (all FLOAT32): A[N*8] | NN[N*8] | top[512] | V[N*64]
    float* out    = (float*)d_out;
    float* outA   = out;
    float* outNN  = out + (size_t)N_PTS * 8;
    float* outTop = out + (size_t)N_PTS * 16;
    float* outV   = out + (size_t)N_PTS * 16 + NSP;

    // ---- beacons: report model mismatches instead of running UB ----
    if ((size_t)ws_size < WS_NEED) {
        k_beacon<<<1, 64, 0, stream>>>(outTop, (float)(ws_size >> 10));
        return;
    }
    if (out_size != (int)((size_t)N_PTS * 16 + NSP + (size_t)N_PTS * 64)) {
        k_beacon<<<1, 64, 0, stream>>>(out, 20000.f + (float)(out_size >> 10));
        return;
    }
    if (in_sizes[0] != N_PTS * 3 || in_sizes[20] != N_PTS * KNN) {
        k_beacon<<<1, 64, 0, stream>>>(out, 30000.f + (float)(in_sizes[0] >> 10));
        return;
    }

    dim3 blk(256);
    int nb = N_PTS / 4;   // 4 waves/block, 1 point/wave

    k_lift<<<nb, blk, 0, stream>>>(coords, feat, lift_w, lift_b, vbufA);

    // steps: A->B (bf16), B->A (bf16), A->outV (f32)
    const u16* vin = vbufA;
    u16* voutB = vbufB;
    for (int t = 0; t < 3; t++) {
        int last = (t == 2);
        k_step<<<nb, blk, 0, stream>>>(vin, last ? nullptr : voutB,
                                       last ? outV : nullptr,
                                       coords, idx,
                                       gvi_w, gvi_b, gp_w, gp_b, gvj_w,
                                       gm1_w, gm1_b, gm2_w, gm2_b, W_w,
                                       ln_g + t * 64, ln_b + t * 64,
                                       scores, last);
        u16* tmp = (u16*)vin; vin = voutB; voutB = tmp;
    }

    k_anchor <<<NSP / 4, blk, 0, stream>>>(scores, coords, wstop, axyz, outTop);
    k_queries<<<NSP / 4, blk, 0, stream>>>(outV, wstop, aq_w, aq_b, q_s);
    k_final  <<<nb, blk, 0, stream>>>(outV, coords, ak_w, ak_b, axyz, q_s,
                                      outA, outNN);
}

// Round 6
// 2692.930 us; speedup vs baseline: 2.0532x; 2.0532x over previous
//
#include <hip/hip_runtime.h>

// SuperpointNeuralOperator on MI355X. Round 6: first optimization pass.
// r5 counters: k_step=98.6% of 5.5ms, Occupancy 12%, VALUBusy 24%, HBM 0.4%,
// LDS_BANK_CONFLICT 1.9e7 -> latency-bound. Fixes:
//  - vjf = v@gvj precomputed per-POINT in k_pre (was per-EDGE LDS tile sweep:
//    256KB LDS traffic + 8-way conflicts per point) -> sGj tile gone.
//  - k_step LDS 54.3KB -> 39KB; __launch_bounds__(256,3) -> 12 waves/CU.
//  - per-edge serial wsum (6 dep shfl x16) -> phase-split: h2[16] in regs,
//    16 interleaved butterflies, then sigmoid+regather pass (ILP).
//  - LN mean/var fused into one interleaved butterfly pair (E[x2]-m2).
// ws layout byte-identical to round-5-proven 17,180,672 B; outV region of
// d_out doubles as bf16 v-scratch mid-pipeline (fully overwritten at t2).

#define N_PTS 65536
#define KNN   16
#define HDIM  64
#define KASEL 8
#define NSP   512
#define GSTRIDE 128   // N_PTS / NSP

typedef unsigned short u16;

__device__ __forceinline__ float bf2f(u16 h) {
    return __uint_as_float(((unsigned int)h) << 16);
}
__device__ __forceinline__ u16 f2bfu(float f) {  // round-to-nearest-even
    unsigned int u = __float_as_uint(f);
    unsigned int r = ((u >> 16) & 1u) + 0x7fffu;
    return (u16)((u + r) >> 16);
}
__device__ __forceinline__ float wsum(float v) {
    #pragma unroll
    for (int o = 32; o > 0; o >>= 1) v += __shfl_xor(v, o, 64);
    return v;
}
__device__ __forceinline__ float gelu_exact(float x) {
    return 0.5f * x * (1.0f + erff(x * 0.70710678118654752440f));
}

// ---------------------------------------------------------------- lift ------
__global__ __launch_bounds__(256) void k_lift(
    const float* __restrict__ coords, const float* __restrict__ feat,
    const float* __restrict__ lw, const float* __restrict__ lb,
    u16* __restrict__ vA)
{
    int lane = threadIdx.x & 63, wid = threadIdx.x >> 6;
    float w[9];
    #pragma unroll
    for (int k = 0; k < 9; k++) w[k] = lw[k * 64 + lane];
    float b = lb[lane];
    int i = blockIdx.x * 4 + wid;
    if (i >= N_PTS) return;
    float in[9];
    #pragma unroll
    for (int k = 0; k < 3; k++) in[k] = coords[i * 3 + k];
    #pragma unroll
    for (int k = 0; k < 6; k++) in[3 + k] = feat[i * 6 + k];
    float acc = b;
    #pragma unroll
    for (int k = 0; k < 9; k++) acc = fmaf(in[k], w[k], acc);
    vA[(size_t)i * 64 + lane] = f2bfu(acc);
}

// ---------------------- k_pre: vjf = v @ gvj (per point, once) --------------
// gvj column `lane` lives in 64 VGPRs; v rows read as wave-uniform broadcast
// loads (compiler scalarizes). 8 points per wave amortize the weight load.
#define PPW 8
__global__ __launch_bounds__(256) void k_pre(
    const u16* __restrict__ vin, const float* __restrict__ gvj,
    u16* __restrict__ vjf)
{
    int lane = threadIdx.x & 63, wid = threadIdx.x >> 6;
    float w[64];
    #pragma unroll
    for (int k = 0; k < 64; k++) w[k] = gvj[k * 64 + lane];
    int base = (blockIdx.x * 4 + wid) * PPW;
    for (int p = 0; p < PPW; p++) {
        int i = base + p;
        const uint2* row = (const uint2*)&vin[(size_t)i * 64];
        float a0 = 0.f, a1 = 0.f, a2 = 0.f, a3 = 0.f;
        #pragma unroll
        for (int c = 0; c < 16; c++) {
            uint2 q = row[c];                       // 4 bf16, wave-uniform addr
            a0 = fmaf(bf2f((u16)(q.x & 0xffffu)), w[4*c+0], a0);
            a1 = fmaf(bf2f((u16)(q.x >> 16)),     w[4*c+1], a1);
            a2 = fmaf(bf2f((u16)(q.y & 0xffffu)), w[4*c+2], a2);
            a3 = fmaf(bf2f((u16)(q.y >> 16)),     w[4*c+3], a3);
        }
        vjf[(size_t)i * 64 + lane] = f2bfu((a0 + a1) + (a2 + a3));
    }
}

// ----------------------------------------------------------- gnn step -------
__global__ __launch_bounds__(256, 3) void k_step(
    const u16* __restrict__ vin, const u16* __restrict__ vjf,
    u16* __restrict__ voutB, float* __restrict__ voutF,
    const float* __restrict__ coords, const int* __restrict__ idxp,
    const float* __restrict__ gvi_w, const float* __restrict__ gvi_b,
    const float* __restrict__ gp_w,  const float* __restrict__ gp_b,
    const float* __restrict__ gm1_w, const float* __restrict__ gm1_b,
    const float* __restrict__ gm2_w, const float* __restrict__ gm2_b,
    const float* __restrict__ W_w,
    const float* __restrict__ ln_gp, const float* __restrict__ ln_bp,
    float* __restrict__ scores, int lastStep)
{
    __shared__ __align__(16) float sVi[64][68];
    __shared__ __align__(16) float sWw[64][68];
    __shared__ __align__(16) float rows[4][3][64];  // [wid][slot][chan]
    int lane = threadIdx.x & 63, wid = threadIdx.x >> 6, tid = threadIdx.x;
    for (int e = tid; e < 4096; e += 256) {
        int k = e >> 6, l = e & 63;
        sVi[l][k] = gvi_w[e];
        sWw[l][k] = W_w[e];
    }
    float gc[64];                               // gm1 column in registers
    #pragma unroll
    for (int k = 0; k < 64; k++) gc[k] = gm1_w[k * 64 + lane];
    float gp0 = gp_w[lane], gp1 = gp_w[64 + lane], gp2 = gp_w[128 + lane];
    float gpb = gp_b[lane], gvib = gvi_b[lane], gm1b = gm1_b[lane];
    float gm2c = gm2_w[lane];
    float gm2b = gm2_b[0];
    float lng = ln_gp[lane], lnb = ln_bp[lane];
    __syncthreads();

    int i = blockIdx.x * 4 + wid;

    float vl = bf2f(vin[(size_t)i * 64 + lane]);
    rows[wid][2][lane] = vl;
    float vi, wv;
    {
        float a0 = 0.f, a1 = 0.f, b0 = 0.f, b1 = 0.f;
        const float* w0 = &sVi[lane][0];
        const float* w1 = &sWw[lane][0];
        #pragma unroll
        for (int kk = 0; kk < 16; kk++) {
            float4 r = *(const float4*)&rows[wid][2][kk * 4];
            float4 x = *(const float4*)(w0 + kk * 4);
            float4 y = *(const float4*)(w1 + kk * 4);
            a0 = fmaf(r.x, x.x, fmaf(r.y, x.y, a0));
            a1 = fmaf(r.z, x.z, fmaf(r.w, x.w, a1));
            b0 = fmaf(r.x, y.x, fmaf(r.y, y.y, b0));
            b1 = fmaf(r.z, y.z, fmaf(r.w, y.w, b1));
        }
        vi = a0 + a1 + gvib;
        wv = b0 + b1;
    }
    float cix = coords[i * 3], ciy = coords[i * 3 + 1], ciz = coords[i * 3 + 2];

    // edge indices -> SGPRs (wave-uniform)
    int js[16];
    {
        const int4* ip = (const int4*)&idxp[(size_t)i * 16];
        #pragma unroll
        for (int q = 0; q < 4; q++) {
            int4 v4 = ip[q];
            js[4*q+0] = __builtin_amdgcn_readfirstlane(v4.x) & (N_PTS - 1);
            js[4*q+1] = __builtin_amdgcn_readfirstlane(v4.y) & (N_PTS - 1);
            js[4*q+2] = __builtin_amdgcn_readfirstlane(v4.z) & (N_PTS - 1);
            js[4*q+3] = __builtin_amdgcn_readfirstlane(v4.w) & (N_PTS - 1);
        }
    }

    // phase A: per edge, h2 = gelu(gm1 @ gelu(posproj + vi + vjf) + b)
    float h2[16];
    #pragma unroll 2
    for (int k = 0; k < KNN; k++) {
        int j = js[k];
        float rx = coords[j * 3]     - cix;      // scalar loads (j uniform)
        float ry = coords[j * 3 + 1] - ciy;
        float rz = coords[j * 3 + 2] - ciz;
        float vjl = bf2f(vjf[(size_t)j * 64 + lane]);
        float g = fmaf(rx, gp0, fmaf(ry, gp1, fmaf(rz, gp2, gpb))) + vi + vjl;
        float h = gelu_exact(g);
        int slot = k & 1;
        rows[wid][slot][lane] = h;               // wave-synchronous broadcast
        float a0 = 0.f, a1 = 0.f, a2 = 0.f, a3 = 0.f;
        #pragma unroll
        for (int kk = 0; kk < 16; kk++) {
            float4 h4 = *(const float4*)&rows[wid][slot][kk * 4];
            a0 = fmaf(h4.x, gc[4*kk+0], a0);
            a1 = fmaf(h4.y, gc[4*kk+1], a1);
            a2 = fmaf(h4.z, gc[4*kk+2], a2);
            a3 = fmaf(h4.w, gc[4*kk+3], a3);
        }
        h2[k] = gelu_exact((a0 + a1) + (a2 + a3) + gm1b);
    }

    // phase B: 16 interleaved butterfly reductions of h2[k]*gm2c
    #pragma unroll
    for (int k = 0; k < KNN; k++) h2[k] *= gm2c;
    #pragma unroll
    for (int o = 32; o > 0; o >>= 1) {
        #pragma unroll
        for (int k = 0; k < KNN; k++) h2[k] += __shfl_xor(h2[k], o, 64);
    }

    // phase C: gate + regather v_j + accumulate
    float integral = 0.f;
    #pragma unroll
    for (int k = 0; k < KNN; k++) {
        float G = 1.f / (1.f + expf(-(h2[k] + gm2b)));
        float vjraw = bf2f(vin[(size_t)js[k] * 64 + lane]);
        integral = fmaf(G, vjraw, integral);
    }
    integral *= (1.f / 16.f);

    // epilogue: relu + LN (fused mean/var butterflies)
    float x = integral + wv;
    x = x > 0.f ? x : 0.f;
    float s1 = x, s2 = x * x;
    #pragma unroll
    for (int o = 32; o > 0; o >>= 1) {
        s1 += __shfl_xor(s1, o, 64);
        s2 += __shfl_xor(s2, o, 64);
    }
    float m   = s1 * (1.f / 64.f);
    float var = fmaxf(s2 * (1.f / 64.f) - m * m, 0.f);
    float vn  = (x - m) * (1.f / sqrtf(var + 1e-5f)) * lng + lnb;

    if (lastStep) {
        voutF[(size_t)i * 64 + lane] = vn;        // final v -> d_out (f32)
        float q = vn * vn;
        #pragma unroll
        for (int o = 32; o > 0; o >>= 1) q += __shfl_xor(q, o, 64);
        if (lane == 0) scores[i] = sqrtf(q);
    } else {
        voutB[(size_t)i * 64 + lane] = f2bfu(vn); // intermediate (bf16)
    }
}

// ------------------------------------------------ strided argmax anchors ----
__global__ __launch_bounds__(256) void k_anchor(
    const float* __restrict__ scores, const float* __restrict__ coords,
    int* __restrict__ wstop, float* __restrict__ axyz, float* __restrict__ outTop)
{
    int lane = threadIdx.x & 63, wid = threadIdx.x >> 6;
    int g = blockIdx.x * 4 + wid;
    if (g >= NSP) return;
    float s1 = scores[g * GSTRIDE + lane];
    float s2 = scores[g * GSTRIDE + 64 + lane];
    float bv; int bi;
    if (s1 >= s2) { bv = s1; bi = lane; } else { bv = s2; bi = 64 + lane; }
    #pragma unroll
    for (int o = 32; o > 0; o >>= 1) {
        float ov = __shfl_xor(bv, o, 64);
        int   oi = __shfl_xor(bi, o, 64);
        if (ov > bv || (ov == bv && oi < bi)) { bv = ov; bi = oi; }
    }
    int top = g * GSTRIDE + bi;
    if (lane == 0) {
        wstop[g] = top;
        outTop[g] = (float)top;
        float ax = coords[top * 3], ay = coords[top * 3 + 1], az = coords[top * 3 + 2];
        axyz[g * 4 + 0] = ax;
        axyz[g * 4 + 1] = ay;
        axyz[g * 4 + 2] = az;
        axyz[g * 4 + 3] = fmaf(ax, ax, fmaf(ay, ay, az * az));
    }
}

// ----------------------------------------- queries = v[top] @ aq + b, /s ----
__global__ __launch_bounds__(256) void k_queries(
    const float* __restrict__ vfin, const int* __restrict__ wstop,
    const float* __restrict__ aq_w, const float* __restrict__ aq_b,
    float* __restrict__ q_s)
{
    __shared__ __align__(16) float rows[4][64];
    int lane = threadIdx.x & 63, wid = threadIdx.x >> 6;
    float w[64];
    #pragma unroll
    for (int k = 0; k < 64; k++) w[k] = aq_w[k * 64 + lane];
    float b = aq_b[lane];
    int g = blockIdx.x * 4 + wid;
    if (g >= NSP) return;
    int tv = wstop[g] & (N_PTS - 1);
    rows[wid][lane] = vfin[(size_t)tv * 64 + lane];
    float acc = b;
    #pragma unroll
    for (int kk = 0; kk < 16; kk++) {
        float4 r = *(const float4*)&rows[wid][kk * 4];
        acc = fmaf(r.x, w[4*kk+0], fmaf(r.y, w[4*kk+1],
              fmaf(r.z, w[4*kk+2], fmaf(r.w, w[4*kk+3], acc))));
    }
    q_s[(size_t)g * 64 + lane] = acc / 2.82842712474619f;   // 64^0.25
}

// ---------------------------- kNN-to-anchors + attention softmax ------------
__global__ __launch_bounds__(256) void k_final(
    const float* __restrict__ vfin, const float* __restrict__ coords,
    const float* __restrict__ ak_w, const float* __restrict__ ak_b,
    const float* __restrict__ axyz, const float* __restrict__ q_s,
    float* __restrict__ outA, float* __restrict__ outNN)
{
    __shared__ __align__(16) float rows[4][64];
    int lane = threadIdx.x & 63, wid = threadIdx.x >> 6;
    float w[64];
    #pragma unroll
    for (int k = 0; k < 64; k++) w[k] = ak_w[k * 64 + lane];
    float kb = ak_b[lane];
    int i = blockIdx.x * 4 + wid;
    if (i >= N_PTS) return;

    float vl = vfin[(size_t)i * 64 + lane];
    rows[wid][lane] = vl;
    float acc = kb;
    #pragma unroll
    for (int kk = 0; kk < 16; kk++) {
        float4 r = *(const float4*)&rows[wid][kk * 4];
        acc = fmaf(r.x, w[4*kk+0], fmaf(r.y, w[4*kk+1],
              fmaf(r.z, w[4*kk+2], fmaf(r.w, w[4*kk+3], acc))));
    }
    float ks = acc / 2.82842712474619f;

    float cx = coords[i * 3], cy = coords[i * 3 + 1], cz = coords[i * 3 + 2];
    float cn2 = fmaf(cx, cx, fmaf(cy, cy, cz * cz));
    float d2v[8];
    #pragma unroll
    for (int m = 0; m < 8; m++) {
        int a = lane + 64 * m;
        float4 av = *(const float4*)&axyz[a * 4];
        float dot = fmaf(cx, av.x, fmaf(cy, av.y, cz * av.z));
        d2v[m] = cn2 + av.w - 2.f * dot;
    }
    unsigned taken = 0;
    int sel[8];
    #pragma unroll
    for (int r = 0; r < KASEL; r++) {
        float bv = 3.4e38f; int bi = 0x7fffffff;
        #pragma unroll
        for (int m = 0; m < 8; m++) {
            if (!((taken >> m) & 1u)) {
                int ai = lane + 64 * m;
                float dv = d2v[m];
                if (dv < bv || (dv == bv && ai < bi)) { bv = dv; bi = ai; }
            }
        }
        #pragma unroll
        for (int o = 32; o > 0; o >>= 1) {
            float ov = __shfl_xor(bv, o, 64);
            int   oi = __shfl_xor(bi, o, 64);
            if (ov < bv || (ov == bv && oi < bi)) { bv = ov; bi = oi; }
        }
        sel[r] = bi & (NSP - 1);
        if ((bi & 63) == lane) taken |= 1u << (bi >> 6);
    }
    float lg[8];
    #pragma unroll
    for (int r = 0; r < KASEL; r++) {
        float q = q_s[(size_t)sel[r] * 64 + lane];
        lg[r] = wsum(ks * q);
    }
    float mx = lg[0];
    #pragma unroll
    for (int r = 1; r < KASEL; r++) mx = fmaxf(mx, lg[r]);
    float e[8], ssum = 0.f;
    #pragma unroll
    for (int r = 0; r < KASEL; r++) { e[r] = expf(lg[r] - mx); ssum += e[r]; }
    if (lane == 0) {
        float inv = 1.f / ssum;
        float4 a0 = make_float4(e[0]*inv, e[1]*inv, e[2]*inv, e[3]*inv);
        float4 a1 = make_float4(e[4]*inv, e[5]*inv, e[6]*inv, e[7]*inv);
        float4 n0 = make_float4((float)sel[0], (float)sel[1], (float)sel[2], (float)sel[3]);
        float4 n1 = make_float4((float)sel[4], (float)sel[5], (float)sel[6], (float)sel[7]);
        *(float4*)&outA [(size_t)i * 8]     = a0;
        *(float4*)&outA [(size_t)i * 8 + 4] = a1;
        *(float4*)&outNN[(size_t)i * 8]     = n0;
        *(float4*)&outNN[(size_t)i * 8 + 4] = n1;
    }
}

// ------------------------------------------------------- beacon kernel -----
__global__ void k_beacon(float* dst, float code) {
    if (threadIdx.x == 0 && blockIdx.x == 0) dst[0] = code;
}

// ---------------------------------------------------------------- launch ----
extern "C" void kernel_launch(void* const* d_in, const int* in_sizes, int n_in,
                              void* d_out, int out_size, void* d_ws, size_t ws_size,
                              hipStream_t stream) {
    (void)n_in;
    const float* coords = (const float*)d_in[0];
    const float* feat   = (const float*)d_in[1];
    const float* lift_w = (const float*)d_in[2];
    const float* lift_b = (const float*)d_in[3];
    const float* gp_w   = (const float*)d_in[4];
    const float* gp_b   = (const float*)d_in[5];
    const float* gvi_w  = (const float*)d_in[6];
    const float* gvi_b  = (const float*)d_in[7];
    const float* gvj_w  = (const float*)d_in[8];
    const float* gm1_w  = (const float*)d_in[9];
    const float* gm1_b  = (const float*)d_in[10];
    const float* gm2_w  = (const float*)d_in[11];
    const float* gm2_b  = (const float*)d_in[12];
    const float* W_w    = (const float*)d_in[13];
    const float* ln_g   = (const float*)d_in[14];
    const float* ln_b   = (const float*)d_in[15];
    const float* ak_w   = (const float*)d_in[16];
    const float* ak_b   = (const float*)d_in[17];
    const float* aq_w   = (const float*)d_in[18];
    const float* aq_b   = (const float*)d_in[19];
    const int* idx      = (const int*)d_in[20];

    // workspace layout: 17,180,672 B, byte-identical to round-5-proven size
    char* ws = (char*)d_ws;
    size_t o = 0;
    u16*   vbufA  = (u16*)  (ws + o); o += (size_t)N_PTS * 64 * 2;  // X
    u16*   vbufB  = (u16*)  (ws + o); o += (size_t)N_PTS * 64 * 2;  // Y
    float* scores = (float*)(ws + o); o += (size_t)N_PTS * 4;
    int*   wstop  = (int*)  (ws + o); o += (size_t)NSP * 4;
    float* axyz   = (float*)(ws + o); o += (size_t)NSP * 4 * 4;
    float* q_s    = (float*)(ws + o); o += (size_t)NSP * 64 * 4;
    const size_t WS_NEED = o;  // 17,180,672

    // d_out layout (all FLOAT32): A[N*8] | NN[N*8] | top[512] | V[N*64]
    float* out    = (float*)d_out;
    float* outA   = out;
    float* outNN  = out + (size_t)N_PTS * 8;
    float* outTop = out + (size_t)N_PTS * 16;
    float* outV   = out + (size_t)N_PTS * 16 + NSP;
    u16*   S      = (u16*)outV;   // bf16 scratch in outV region (8.39MB of
                                  // 16.78MB; fully overwritten by t2's f32 v)

    // ---- beacons: report model mismatches instead of running UB ----
    if ((size_t)ws_size < WS_NEED) {
        k_beacon<<<1, 64, 0, stream>>>(outTop, (float)(ws_size >> 10));
        return;
    }
    if (out_size != (int)((size_t)N_PTS * 16 + NSP + (size_t)N_PTS * 64)) {
        k_beacon<<<1, 64, 0, stream>>>(out, 20000.f + (float)(out_size >> 10));
        return;
    }
    if (in_sizes[0] != N_PTS * 3 || in_sizes[20] != N_PTS * KNN) {
        k_beacon<<<1, 64, 0, stream>>>(out, 30000.f + (float)(in_sizes[0] >> 10));
        return;
    }

    dim3 blk(256);
    int nb  = N_PTS / 4;            // k_step/k_final: 1 point per wave
    int nbp = N_PTS / (4 * PPW);    // k_pre: 8 points per wave

    k_lift<<<nb, blk, 0, stream>>>(coords, feat, lift_w, lift_b, vbufA);

    // rotation (all v/vjf bf16): X --lift
    // t0: pre(X)->Y;  step(X,Y)->S
    // t1: pre(S)->X;  step(S,X)->Y
    // t2: pre(Y)->X;  step(Y,X)->outV(f32) + scores
    const u16* vcur = vbufA;
    u16* jbuf = vbufB;
    u16* vnxt = S;
    for (int t = 0; t < 3; t++) {
        int last = (t == 2);
        k_pre<<<nbp, blk, 0, stream>>>(vcur, gvj_w, jbuf);
        k_step<<<nb, blk, 0, stream>>>(vcur, jbuf,
                                       last ? nullptr : vnxt,
                                       last ? outV : nullptr,
                                       coords, idx,
                                       gvi_w, gvi_b, gp_w, gp_b,
                                       gm1_w, gm1_b, gm2_w, gm2_b, W_w,
                                       ln_g + t * 64, ln_b + t * 64,
                                       scores, last);
        // rotate: new vcur = vnxt; new jbuf = old vcur; new vnxt = old jbuf
        u16* oldcur = (u16*)vcur;
        vcur = vnxt;
        vnxt = jbuf;
        jbuf = oldcur;
    }

    k_anchor <<<NSP / 4, blk, 0, stream>>>(scores, coords, wstop, axyz, outTop);
    k_queries<<<NSP / 4, blk, 0, stream>>>(outV, wstop, aq_w, aq_b, q_s);
    k_final  <<<nb, blk, 0, stream>>>(outV, coords, ak_w, ak_b, axyz, q_s,
                                      outA, outNN);
}